// Round 6
// baseline (1401.889 us; speedup 1.0000x reference)
//
#include <hip/hip_runtime.h>
#include <hip/hip_cooperative_groups.h>

namespace cg = cooperative_groups;

// ResidualConvLSTM2D on MI355X (gfx950) — R6: single cooperative kernel.
// All 16 timesteps in one dispatch; grid.sync() between steps.
//   - weight tile (64 gate-cols x 864 k) LDS-RESIDENT, loaded once per block
//   - c-state in VGPRs for the whole sequence (no global c traffic)
//   - K-loop barrier-free (A from staged patch, B from resident LDS)
//   - residual 1x1 conv folded into the MFMA as an extra B-frag at s==12
//     (center-tap x-channels), bias added in epilogue
// Block (256 of them, 1/CU): pixel-group 4 rows x 64 cols of one batch x
// n-quarter q (16 f-channels x 4 gates; nloc = g*16+fi, orig n = g*64+q*16+fi).
// Two K-loop passes per t (col-halves of 32).
//
// ws layout (4.44 MB):
//   [0, 446464)        WQ bf16 [4][64][872]  (per-quarter, padded rows)
//   [446464, 451584)   Wp bf16 [4][16][40]
//   [458752, +2MB)     h ping  bf16 [4][64][64][64]
//   [2555904, +2MB)    h pong  bf16
#define B_ 4
#define T_ 16
#define H_ 64
#define W_ 64
#define CIN 32
#define F_ 64
#define NCH 256
#define KSTEPS 27

#define OFF_H0 458752
#define OFF_H1 2555904

// LDS layout (bytes)
#define L_WLDS  0        // [64][872] sh = 111616
#define L_WPB   111616   // [16][40] sh = 1280
#define L_PATCH 112896   // patch [204][104] sh = 42432; overlay:
                         //   gact fp32 [128][68] = 34816 @L_PATCH
                         //   resl fp32 [128][20] = 10240 @L_PATCH+34816
#define SMEM_BYTES 157952

typedef __attribute__((ext_vector_type(8))) short short8;
typedef __attribute__((ext_vector_type(4))) float floatx4;
typedef __attribute__((address_space(3))) unsigned int  lds_u32;
typedef __attribute__((address_space(1))) const unsigned int g_u32;

__device__ __forceinline__ unsigned short f2bf(float f) {
  union { float f; unsigned u; } v; v.f = f;
  unsigned r = v.u + 0x7FFFu + ((v.u >> 16) & 1u);   // round-to-nearest-even
  return (unsigned short)(r >> 16);
}

__device__ __forceinline__ float tanh_fast(float z) {
  float e = __expf(2.0f * z);
  return 1.0f - 2.0f * __builtin_amdgcn_rcpf(e + 1.0f);
}

// Build the combined weight image:
//  [0, 223232)        WQ[q][nloc][872]: k<864 -> weight(k, n=g*64+q*16+fi), else 0
//  [223232, 225792)   wp[q][fi][40]:   c<32  -> Wp[c][q*16+fi], else 0
__global__ void prep_weights(const float* __restrict__ Wx, const float* __restrict__ Wh,
                             const float* __restrict__ Wp, unsigned short* __restrict__ img) {
  int idx = blockIdx.x * 256 + threadIdx.x;            // 0..225791
  unsigned short v = 0;
  if (idx < 223232) {
    int q = idx / 55808; int r = idx - q * 55808;
    int nloc = r / 872;  int k = r - nloc * 872;
    if (k < 864) {
      int g = nloc >> 4, fi = nloc & 15;
      int n = g * 64 + q * 16 + fi;
      int tap = k / 96, ch = k - tap * 96;
      float f = (ch < CIN) ? Wx[(tap * CIN + ch) * NCH + n]
                           : Wh[(tap * F_ + (ch - CIN)) * NCH + n];
      v = f2bf(f);
    }
  } else {
    int r = idx - 223232;                              // 0..2559
    int q = r / 640; int r2 = r - q * 640;
    int fi = r2 / 40; int c = r2 - fi * 40;
    if (c < 32) v = f2bf(Wp[c * F_ + q * 16 + fi]);
  }
  img[idx] = v;
}

// Zero h ping (2 MB): 512 blocks x 256 threads x 16 B.
__global__ void prep_zero_h(float4* __restrict__ p) {
  int idx = blockIdx.x * 256 + threadIdx.x;
  p[idx] = make_float4(0.f, 0.f, 0.f, 0.f);
}

__global__ __launch_bounds__(256)
void lstm_all(const float* __restrict__ x, const float* __restrict__ bias,
              const float* __restrict__ bp, const unsigned short* __restrict__ wimg,
              unsigned short* __restrict__ h0g, unsigned short* __restrict__ h1g,
              float* __restrict__ out)
{
  extern __shared__ __align__(16) char smem[];
  short* wlds  = (short*)(smem + L_WLDS);
  short* wpb   = (short*)(smem + L_WPB);
  short* patch = (short*)(smem + L_PATCH);
  float* gact  = (float*)(smem + L_PATCH);
  float* resl  = (float*)(smem + L_PATCH + 34816);

  const int tid  = threadIdx.x;
  const int w    = tid >> 6;
  const int lane = tid & 63;
  const int quad = lane >> 4;
  const int lr   = lane & 15;

  const int bid = blockIdx.x;
  const int q   = bid & 3;            // n-quarter (16 f x 4 gates)
  const int grp = bid >> 2;           // pixel group: 4 rows x 64 cols
  const int b   = grp >> 4;
  const int y0  = (grp & 15) << 2;

  // ---- one-time: resident weight tile via DMA (109 x 1KB chunks)
  {
    const unsigned short* src = wimg + q * 55808;
    __attribute__((address_space(3))) unsigned short* d =
        (__attribute__((address_space(3))) unsigned short*)wlds;
    for (int j = w; j < 109; j += 4)
      __builtin_amdgcn_global_load_lds((g_u32*)(src + j * 512 + lane * 8),
                                       (lds_u32*)(d + j * 512 + lane * 8), 16, 0, 0);
  }
  if (tid < 80) {                     // wp block: 1280 B
    uint4 v = *(const uint4*)(wimg + 223232 + q * 640 + tid * 8);
    *(uint4*)(wpb + tid * 8) = v;
  }

  float bias_r[4];
  #pragma unroll
  for (int nf = 0; nf < 4; nf++) bias_r[nf] = bias[nf * 64 + q * 16 + lr];
  const float bp_r = bp[q * 16 + lr];

  int paoff[2];
  #pragma unroll
  for (int mf = 0; mf < 2; mf++) {
    int p = (w * 2 + mf) * 16 + lr;
    paoff[mf] = ((p >> 5) * 34 + (p & 31)) * 104 + quad * 8;
  }
  int wboff[4];
  #pragma unroll
  for (int nf = 0; nf < 4; nf++) wboff[nf] = (nf * 16 + lr) * 872 + quad * 8;
  const int wpoff = lr * 40 + quad * 8;

  float cst[2][8];
  #pragma unroll
  for (int pp = 0; pp < 2; pp++)
    #pragma unroll
    for (int j = 0; j < 8; j++) cst[pp][j] = 0.f;

  #pragma unroll 1
  for (int t = 0; t < T_; ++t) {
    const unsigned short* hp = (t & 1) ? h1g : h0g;
    unsigned short*       hn = (t & 1) ? h0g : h1g;

    #pragma unroll
    for (int pp = 0; pp < 2; ++pp) {
      const int xbase = pp << 5;
      __syncthreads();                // prev pass's gact/resl reads done

      // ---- stage patch: 6 rows x 34 cols x 96 ch (x bf16 | h bf16)
      if (tid < 204) {
        int sy = tid / 34, sx = tid - sy * 34;
        int yy = y0 + sy - 1, xx = xbase + sx - 1;
        short* dst = patch + tid * 104;
        if (yy >= 0 && yy < H_ && xx >= 0 && xx < W_) {
          const float4* xs = (const float4*)(x + ((((b * T_ + t) * H_ + yy) * W_ + xx) * CIN));
          #pragma unroll
          for (int j = 0; j < 4; j++) {
            float4 f0 = xs[2 * j];
            float4 f1 = xs[2 * j + 1];
            union { short8 v; unsigned short u[8]; } pk;
            pk.u[0] = f2bf(f0.x); pk.u[1] = f2bf(f0.y); pk.u[2] = f2bf(f0.z); pk.u[3] = f2bf(f0.w);
            pk.u[4] = f2bf(f1.x); pk.u[5] = f2bf(f1.y); pk.u[6] = f2bf(f1.z); pk.u[7] = f2bf(f1.w);
            ((short8*)dst)[j] = pk.v;
          }
          const uint4* hs = (const uint4*)(hp + ((b * H_ + yy) * W_ + xx) * F_);
          uint4* d2 = (uint4*)(dst + 32);
          #pragma unroll
          for (int j = 0; j < 8; j++) d2[j] = hs[j];
        } else {
          uint4 z = make_uint4(0, 0, 0, 0);
          uint4* d4 = (uint4*)dst;
          #pragma unroll
          for (int j = 0; j < 12; j++) d4[j] = z;
        }
      }
      __syncthreads();                // patch (and, first time, weight DMA) visible

      // ---- K loop: 27 steps, barrier-free (A: patch LDS, B: resident LDS)
      floatx4 acc[2][4], accr[2];
      #pragma unroll
      for (int mf = 0; mf < 2; mf++) {
        accr[mf] = (floatx4){0.f, 0.f, 0.f, 0.f};
        #pragma unroll
        for (int nf = 0; nf < 4; nf++) acc[mf][nf] = (floatx4){0.f, 0.f, 0.f, 0.f};
      }
      #pragma unroll
      for (int s = 0; s < KSTEPS; ++s) {
        const int g3 = s / 3;
        const int c0 = (s - g3 * 3) * 32;
        const int koff = ((g3 / 3) * 34 + (g3 % 3)) * 104 + c0;   // compile-time
        short8 afr[2];
        afr[0] = *(const short8*)(patch + paoff[0] + koff);
        afr[1] = *(const short8*)(patch + paoff[1] + koff);
        #pragma unroll
        for (int nf = 0; nf < 4; nf++) {
          short8 bfr = *(const short8*)(wlds + wboff[nf] + s * 32);
          acc[0][nf] = __builtin_amdgcn_mfma_f32_16x16x32_bf16(afr[0], bfr, acc[0][nf], 0, 0, 0);
          acc[1][nf] = __builtin_amdgcn_mfma_f32_16x16x32_bf16(afr[1], bfr, acc[1][nf], 0, 0, 0);
        }
        if (s == 12) {                // center tap, x-channels: residual 1x1
          short8 br = *(const short8*)(wpb + wpoff);
          accr[0] = __builtin_amdgcn_mfma_f32_16x16x32_bf16(afr[0], br, accr[0], 0, 0, 0);
          accr[1] = __builtin_amdgcn_mfma_f32_16x16x32_bf16(afr[1], br, accr[1], 0, 0, 0);
        }
      }
      __syncthreads();                // patch reads done (gact/resl overlay)

      // ---- activations -> gact[px][nloc], residual -> resl[px][.]
      #pragma unroll
      for (int mf = 0; mf < 2; mf++) {
        #pragma unroll
        for (int nf = 0; nf < 4; nf++)
          #pragma unroll
          for (int r = 0; r < 4; r++) {
            int px = (w * 2 + mf) * 16 + quad * 4 + r;    // D row = quad*4+reg
            float z = acc[mf][nf][r] + bias_r[nf];
            float a;
            if (nf == 2) a = tanh_fast(z);                // candidate gate
            else {
              a = __builtin_fmaf(z, 0.2f, 0.5f);
              a = fminf(fmaxf(a, 0.f), 1.f);
            }
            gact[px * 68 + nf * 16 + lr] = a;
          }
        #pragma unroll
        for (int r = 0; r < 4; r++) {
          int px = (w * 2 + mf) * 16 + quad * 4 + r;
          resl[px * 20 + lr] = accr[mf][r] + bp_r;
        }
      }
      __syncthreads();                // gact + resl visible

      // ---- LSTM cell: thread -> (px = tid>>1, f-octet fo)
      const int px = tid >> 1;
      const int fo = (tid & 1) << 3;
      const int gy = y0 + (px >> 5), gx = xbase + (px & 31);
      const int hbase = ((b * H_ + gy) * W_ + gx) * F_ + q * 16 + fo;
      const int outb  = (((b * T_ + t) * H_ + gy) * W_ + gx) * F_ + q * 16 + fo;
      union { unsigned short hv[8]; uint4 u; } hu;
      #pragma unroll
      for (int j4 = 0; j4 < 2; ++j4) {
        float4 gi = *(const float4*)(gact + px * 68 +  0 + fo + j4 * 4);
        float4 gf = *(const float4*)(gact + px * 68 + 16 + fo + j4 * 4);
        float4 gg = *(const float4*)(gact + px * 68 + 32 + fo + j4 * 4);
        float4 go = *(const float4*)(gact + px * 68 + 48 + fo + j4 * 4);
        float4 rs = *(const float4*)(resl + px * 20 + fo + j4 * 4);
        float ivv[4] = {gi.x, gi.y, gi.z, gi.w};
        float fvv[4] = {gf.x, gf.y, gf.z, gf.w};
        float gvv[4] = {gg.x, gg.y, gg.z, gg.w};
        float ovv[4] = {go.x, go.y, go.z, go.w};
        float rsv[4] = {rs.x, rs.y, rs.z, rs.w};
        float o4[4];
        #pragma unroll
        for (int e = 0; e < 4; ++e) {
          int j = j4 * 4 + e;
          float cn = fvv[e] * cst[pp][j] + ivv[e] * gvv[e];
          float h  = ovv[e] * tanh_fast(cn);
          cst[pp][j] = cn;
          hu.hv[j] = f2bf(h);
          o4[e] = h + rsv[e];
        }
        *(float4*)(out + outb + j4 * 4) = make_float4(o4[0], o4[1], o4[2], o4[3]);
      }
      *(uint4*)(hn + hbase) = hu.u;
    }

    __threadfence();                  // release h writes to device scope
    cg::this_grid().sync();           // all h written before next t's staging
  }
}

extern "C" void kernel_launch(void* const* d_in, const int* in_sizes, int n_in,
                              void* d_out, int out_size, void* d_ws, size_t ws_size,
                              hipStream_t stream) {
  const float* x    = (const float*)d_in[0];
  const float* Wx   = (const float*)d_in[1];
  const float* Wh   = (const float*)d_in[2];
  const float* bias = (const float*)d_in[3];
  const float* Wp   = (const float*)d_in[4];
  const float* bp   = (const float*)d_in[5];
  float* out = (float*)d_out;

  unsigned short* wimg = (unsigned short*)d_ws;
  unsigned short* h0   = (unsigned short*)((char*)d_ws + OFF_H0);
  unsigned short* h1   = (unsigned short*)((char*)d_ws + OFF_H1);

  hipFuncSetAttribute(reinterpret_cast<const void*>(lstm_all),
                      hipFuncAttributeMaxDynamicSharedMemorySize, SMEM_BYTES);

  hipLaunchKernelGGL(prep_weights, dim3(882), dim3(256), 0, stream, Wx, Wh, Wp, wimg);
  hipLaunchKernelGGL(prep_zero_h, dim3(512), dim3(256), 0, stream,
                     (float4*)((char*)d_ws + OFF_H0));

  const float* xa = x; const float* ba = bias; const float* bpa = bp;
  const unsigned short* wa = wimg;
  unsigned short* h0a = h0; unsigned short* h1a = h1;
  float* oa = out;
  void* args[] = {&xa, &ba, &bpa, &wa, &h0a, &h1a, &oa};
  hipLaunchCooperativeKernel(reinterpret_cast<const void*>(lstm_all),
                             dim3(256), dim3(256), args, SMEM_BYTES, stream);
}